// Round 1
// baseline (1794.655 us; speedup 1.0000x reference)
//
#include <hip/hip_runtime.h>

// SNN layer: currents[t,b,o] = sum_i x[b,i,t] * w[i,o]  (fp64 for exactness vs np ref)
// then sequential LIF scan over t with spike output (binary -> must match ref decisions).
//
// x: [32][1024][1000] fp32, w: [1024][1024] fp32, out: [32][1024][1000] fp32 (0/1)
//
// ws layout: [0, 256KB)   : v-state, 32*1024 doubles (carried across T-chunks)
//            [256KB, ...) : current chunk buffer, Tc * 32 * 1024 doubles

#define NB 32
#define NI 1024
#define NO 1024
#define NT 1000
#define TT 128   // t-tile per block
#define OT 64    // o-tile per block
#define KI 16    // k (i) tile

__global__ __launch_bounds__(256)
void snn_gemm_f64(const float* __restrict__ x, const float* __restrict__ w,
                  double* __restrict__ cur, int t0, int len)
{
    __shared__ float As[KI][TT];   // 8 KB  (i-major, t contiguous)
    __shared__ float Bs[KI][OT];   // 4 KB  (i-major, o contiguous)

    const int tid = threadIdx.x;
    const int tx  = tid & 15;            // o sub-tile (4 o each)
    const int ty  = tid >> 4;            // t sub-tile (8 t each)
    const int tt0 = t0 + blockIdx.x * TT;
    const int o0  = blockIdx.y * OT;
    const int b   = blockIdx.z;

    const float* xb = x + (size_t)b * NI * NT;

    double acc[8][4];
#pragma unroll
    for (int i = 0; i < 8; ++i)
#pragma unroll
        for (int j = 0; j < 4; ++j) acc[i][j] = 0.0;

    // staging decomposition
    const int ar = tid >> 5;   // 0..7  (A row, +8 for second row)
    const int ac = tid & 31;   // 0..31 (A col in float4 units)
    const int br = tid >> 4;   // 0..15 (B row)
    const int bc = tid & 15;   // 0..15 (B col in float4 units)
    const int at = tt0 + ac * 4;   // global t of this thread's A float4 (mult of 4)

    for (int i0 = 0; i0 < NI; i0 += KI) {
        float4 a0 = make_float4(0.f, 0.f, 0.f, 0.f);
        float4 a1 = a0;
        if (at < NT) {   // NT % 4 == 0, at % 4 == 0 -> whole float4 in bounds
            a0 = *(const float4*)(xb + (size_t)(i0 + ar) * NT + at);
            a1 = *(const float4*)(xb + (size_t)(i0 + ar + 8) * NT + at);
        }
        const float4 bv = *(const float4*)(w + (size_t)(i0 + br) * NO + (o0 + bc * 4));

        __syncthreads();   // previous iteration's LDS reads done
        *(float4*)&As[ar][ac * 4]     = a0;
        *(float4*)&As[ar + 8][ac * 4] = a1;
        *(float4*)&Bs[br][bc * 4]     = bv;
        __syncthreads();

#pragma unroll
        for (int k = 0; k < KI; ++k) {
            const float4 fa0 = *(const float4*)&As[k][ty * 8];
            const float4 fa1 = *(const float4*)&As[k][ty * 8 + 4];
            const float4 fb  = *(const float4*)&Bs[k][tx * 4];
            const double ad[8] = {(double)fa0.x, (double)fa0.y, (double)fa0.z, (double)fa0.w,
                                  (double)fa1.x, (double)fa1.y, (double)fa1.z, (double)fa1.w};
            const double bd[4] = {(double)fb.x, (double)fb.y, (double)fb.z, (double)fb.w};
#pragma unroll
            for (int i = 0; i < 8; ++i)
#pragma unroll
                for (int j = 0; j < 4; ++j)
                    acc[i][j] = fma(ad[i], bd[j], acc[i][j]);
        }
    }

    const int tend = t0 + len;
#pragma unroll
    for (int i = 0; i < 8; ++i) {
        const int tg = tt0 + ty * 8 + i;
        if (tg < tend) {
            double* dst = cur + ((size_t)(tg - t0) * NB + b) * NO + (o0 + tx * 4);
            *(double2*)(dst)     = make_double2(acc[i][0], acc[i][1]);
            *(double2*)(dst + 2) = make_double2(acc[i][2], acc[i][3]);
        }
    }
}

// LIF scan: one thread per (b,o); cur chunk is [tc][b*NO+o] fp64; out is [b*NO+o][t] fp32.
__global__ __launch_bounds__(64)
void snn_scan_f64(const double* __restrict__ cur, float* __restrict__ out,
                  double* __restrict__ vstate, int t0, int len)
{
    const int gid = blockIdx.x * 64 + threadIdx.x;   // b*NO + o
    const double dt = 0.001 / 50.0;                  // MS / TAU, IEEE double, matches python

    double v = (t0 == 0) ? 0.0 : vstate[gid];
    const double* cp = cur + gid;                    // stride NB*NO per t-step
    float* op = out + (size_t)gid * NT + t0;         // thread-contiguous in t

    const size_t ts = (size_t)NB * NO;               // 32768
    const int ng = len >> 2;                         // len always multiple of 4

    double c0 = cp[0], c1 = cp[ts], c2 = cp[2 * ts], c3 = cp[3 * ts];
    for (int g = 0; g < ng; ++g) {
        double n0 = 0.0, n1 = 0.0, n2 = 0.0, n3 = 0.0;
        if (g + 1 < ng) {
            const double* q = cp + (size_t)(4 * (g + 1)) * ts;
            n0 = q[0]; n1 = q[ts]; n2 = q[2 * ts]; n3 = q[3 * ts];
        }
        float4 s;
        v = v + (c0 - v) * dt; { bool sp = (v >= 1.0); s.x = sp ? 1.0f : 0.0f; if (sp) v = 0.0; }
        v = v + (c1 - v) * dt; { bool sp = (v >= 1.0); s.y = sp ? 1.0f : 0.0f; if (sp) v = 0.0; }
        v = v + (c2 - v) * dt; { bool sp = (v >= 1.0); s.z = sp ? 1.0f : 0.0f; if (sp) v = 0.0; }
        v = v + (c3 - v) * dt; { bool sp = (v >= 1.0); s.w = sp ? 1.0f : 0.0f; if (sp) v = 0.0; }
        *(float4*)op = s;
        op += 4;
        c0 = n0; c1 = n1; c2 = n2; c3 = n3;
    }
    vstate[gid] = v;
}

extern "C" void kernel_launch(void* const* d_in, const int* in_sizes, int n_in,
                              void* d_out, int out_size, void* d_ws, size_t ws_size,
                              hipStream_t stream)
{
    const float* x = (const float*)d_in[0];
    const float* w = (const float*)d_in[1];
    float* out = (float*)d_out;

    const size_t vbytes = (size_t)NB * NO * sizeof(double);   // 256 KB
    double* vstate = (double*)d_ws;
    double* curbuf = (double*)((char*)d_ws + vbytes);

    const size_t per_t = (size_t)NB * NO * sizeof(double);    // 256 KB per t-step
    size_t avail = (ws_size > vbytes) ? (ws_size - vbytes) : 0;
    int Tc = (int)((avail / per_t < (size_t)NT) ? (avail / per_t) : (size_t)NT);
    Tc &= ~3;                 // multiple of 4 (keeps float4 store alignment, len%4==0)
    if (Tc < 4) Tc = 4;       // assume ws_size is at least ~1.3 MB

    for (int t0 = 0; t0 < NT; t0 += Tc) {
        const int len = (NT - t0 < Tc) ? (NT - t0) : Tc;
        dim3 gg((len + TT - 1) / TT, NO / OT, NB);
        snn_gemm_f64<<<gg, 256, 0, stream>>>(x, w, curbuf, t0, len);
        snn_scan_f64<<<(NB * NO) / 64, 64, 0, stream>>>(curbuf, out, vstate, t0, len);
    }
}

// Round 2
// 1634.419 us; speedup vs baseline: 1.0980x; 1.0980x over previous
//
#include <hip/hip_runtime.h>

// SNN layer: currents[t,b,o] = sum_i x[b,i,t] * w[i,o]  (fp64 for decision-exactness
// vs the numpy fp64 reference -- output is binary spikes, any flipped decision fails),
// then sequential LIF scan over t.
//
// x: [32][1024][1000] fp32, w: [1024][1024] fp32, out: [32][1024][1000] fp32 (0/1)
//
// Round 2: 128x128 block tile, 8x8 fp64 acc per thread. Per k-step: 64 v_fma_f64
// (256 cyc) vs 16 v_cvt_f64_f32 + 4 ds_read_b128 -> ~78% FMA issue fraction
// (round 1 was 32 FMA vs 12 cvt -> 53% of fp64 peak measured).
//
// ws layout: [0, 256KB)   : v-state, 32*1024 doubles (carried across T-chunks)
//            [256KB, ...) : current chunk buffer, Tc * 32 * 1024 doubles

#define NB 32
#define NI 1024
#define NO 1024
#define NT 1000
#define TT 128   // t-tile per block
#define OT 128   // o-tile per block
#define KI 16    // k (i) tile

__global__ __launch_bounds__(256, 2)
void snn_gemm_f64(const float* __restrict__ x, const float* __restrict__ w,
                  double* __restrict__ cur, int t0, int len)
{
    __shared__ float As[KI][TT];   // 8 KB  (i-major, t contiguous)
    __shared__ float Bs[KI][OT];   // 8 KB  (i-major, o contiguous)

    const int tid = threadIdx.x;
    const int tx  = tid & 15;            // o sub-tile: o = tx*4+{0..3} and 64+tx*4+{0..3}
    const int ty  = tid >> 4;            // t sub-tile: t = ty*8+{0..7}
    const int tt0 = t0 + blockIdx.x * TT;
    const int o0  = blockIdx.y * OT;
    const int b   = blockIdx.z;

    const float* xb = x + (size_t)b * NI * NT;

    double acc[8][8];   // [t][o]
#pragma unroll
    for (int i = 0; i < 8; ++i)
#pragma unroll
        for (int j = 0; j < 8; ++j) acc[i][j] = 0.0;

    // staging decomposition: 16 rows x 128 cols, 2 float4 per thread per tile
    const int sr = tid >> 5;         // 0..7 (rows sr and sr+8)
    const int sc = (tid & 31) * 4;   // 0,4,...,124
    const int at = tt0 + sc;         // global t of this thread's A float4

    for (int i0 = 0; i0 < NI; i0 += KI) {
        float4 a0 = make_float4(0.f, 0.f, 0.f, 0.f);
        float4 a1 = a0;
        if (at < NT) {   // NT%4==0, at%4==0 -> whole float4 in bounds when at<NT
            a0 = *(const float4*)(xb + (size_t)(i0 + sr) * NT + at);
            a1 = *(const float4*)(xb + (size_t)(i0 + sr + 8) * NT + at);
        }
        const float4 b0 = *(const float4*)(w + (size_t)(i0 + sr) * NO + (o0 + sc));
        const float4 b1 = *(const float4*)(w + (size_t)(i0 + sr + 8) * NO + (o0 + sc));

        __syncthreads();   // previous iteration's LDS reads done
        *(float4*)&As[sr][sc]     = a0;
        *(float4*)&As[sr + 8][sc] = a1;
        *(float4*)&Bs[sr][sc]     = b0;
        *(float4*)&Bs[sr + 8][sc] = b1;
        __syncthreads();

#pragma unroll
        for (int k = 0; k < KI; ++k) {
            // A: banks (ty*8)%32 per wave ty in {0..3} -> conflict-free
            const float4 fa0 = *(const float4*)&As[k][ty * 8];
            const float4 fa1 = *(const float4*)&As[k][ty * 8 + 4];
            // B: two groups 64 apart -> 2 addrs per bank group = 2-way = free
            const float4 fb0 = *(const float4*)&Bs[k][tx * 4];
            const float4 fb1 = *(const float4*)&Bs[k][tx * 4 + 64];
            const double ad[8] = {(double)fa0.x, (double)fa0.y, (double)fa0.z, (double)fa0.w,
                                  (double)fa1.x, (double)fa1.y, (double)fa1.z, (double)fa1.w};
            const double bd[8] = {(double)fb0.x, (double)fb0.y, (double)fb0.z, (double)fb0.w,
                                  (double)fb1.x, (double)fb1.y, (double)fb1.z, (double)fb1.w};
#pragma unroll
            for (int i = 0; i < 8; ++i)
#pragma unroll
                for (int j = 0; j < 8; ++j)
                    acc[i][j] = fma(ad[i], bd[j], acc[i][j]);
        }
    }

    const int tend = t0 + len;
#pragma unroll
    for (int i = 0; i < 8; ++i) {
        const int tg = tt0 + ty * 8 + i;
        if (tg < tend) {
            double* dst = cur + ((size_t)(tg - t0) * NB + b) * NO + o0;
            *(double2*)(dst + tx * 4)          = make_double2(acc[i][0], acc[i][1]);
            *(double2*)(dst + tx * 4 + 2)      = make_double2(acc[i][2], acc[i][3]);
            *(double2*)(dst + 64 + tx * 4)     = make_double2(acc[i][4], acc[i][5]);
            *(double2*)(dst + 64 + tx * 4 + 2) = make_double2(acc[i][6], acc[i][7]);
        }
    }
}

// LIF scan: one thread per (b,o); cur chunk is [tc][b*NO+o] fp64; out is [b*NO+o][t] fp32.
// Depth-16 prefetch (two 8-groups in flight) -> latency ceiling ~11 TB/s > HBM BW.
__global__ __launch_bounds__(64)
void snn_scan_f64(const double* __restrict__ cur, float* __restrict__ out,
                  double* __restrict__ vstate, int t0, int len)
{
    const int gid = blockIdx.x * 64 + threadIdx.x;   // b*NO + o
    const double dt = 0.001 / 50.0;                  // MS / TAU, IEEE double, matches python

    double v = (t0 == 0) ? 0.0 : vstate[gid];
    const double* cp = cur + gid;                    // stride NB*NO per t-step
    float* op = out + (size_t)gid * NT + t0;         // thread-contiguous in t

    const size_t ts = (size_t)NB * NO;               // 32768
    const int ng = len >> 3;                         // len always multiple of 8

    double c[8], n[8];
#pragma unroll
    for (int j = 0; j < 8; ++j) c[j] = cp[(size_t)j * ts];
#pragma unroll
    for (int j = 0; j < 8; ++j) n[j] = (ng > 1) ? cp[(size_t)(8 + j) * ts] : 0.0;

    for (int g = 0; g < ng; ++g) {
        double m[8];
        if (g + 2 < ng) {
            const double* q = cp + (size_t)(8 * (g + 2)) * ts;
#pragma unroll
            for (int j = 0; j < 8; ++j) m[j] = q[(size_t)j * ts];
        } else {
#pragma unroll
            for (int j = 0; j < 8; ++j) m[j] = 0.0;
        }
        float s[8];
#pragma unroll
        for (int j = 0; j < 8; ++j) {
            v = v + (c[j] - v) * dt;
            const bool sp = (v >= 1.0);
            s[j] = sp ? 1.0f : 0.0f;
            if (sp) v = 0.0;
        }
        *(float4*)op       = make_float4(s[0], s[1], s[2], s[3]);
        *(float4*)(op + 4) = make_float4(s[4], s[5], s[6], s[7]);
        op += 8;
#pragma unroll
        for (int j = 0; j < 8; ++j) { c[j] = n[j]; n[j] = m[j]; }
    }
    vstate[gid] = v;
}

extern "C" void kernel_launch(void* const* d_in, const int* in_sizes, int n_in,
                              void* d_out, int out_size, void* d_ws, size_t ws_size,
                              hipStream_t stream)
{
    const float* x = (const float*)d_in[0];
    const float* w = (const float*)d_in[1];
    float* out = (float*)d_out;

    const size_t vbytes = (size_t)NB * NO * sizeof(double);   // 256 KB
    double* vstate = (double*)d_ws;
    double* curbuf = (double*)((char*)d_ws + vbytes);

    const size_t per_t = (size_t)NB * NO * sizeof(double);    // 256 KB per t-step
    size_t avail = (ws_size > vbytes) ? (ws_size - vbytes) : 0;
    int Tc = (int)((avail / per_t < (size_t)NT) ? (avail / per_t) : (size_t)NT);
    Tc &= ~7;                 // multiple of 8 (scan groups; 1000%8==0 so every len is too)
    if (Tc < 8) Tc = 8;       // ws_size is comfortably larger in practice

    for (int t0 = 0; t0 < NT; t0 += Tc) {
        const int len = (NT - t0 < Tc) ? (NT - t0) : Tc;
        dim3 gg((len + TT - 1) / TT, NO / OT, NB);
        snn_gemm_f64<<<gg, 256, 0, stream>>>(x, w, curbuf, t0, len);
        snn_scan_f64<<<(NB * NO) / 64, 64, 0, stream>>>(curbuf, out, vstate, t0, len);
    }
}

// Round 4
// 1524.794 us; speedup vs baseline: 1.1770x; 1.0719x over previous
//
#include <hip/hip_runtime.h>

// SNN layer: currents[t,b,o] = sum_i x[b,i,t] * w[i,o] in fp64 (binary spike output
// demands decision-exactness vs the numpy fp64 ref), then sequential LIF scan.
//
// Round 4: self-calibrating f64 MFMA. Round 3's v_mfma_f64_16x16x4f64 attempt
// produced wrong output; the f64 C/D register->row mapping is not reliably the
// same as the (m89-verified) 32-bit-accumulator shapes. So: probe the mapping at
// runtime with an exact integer-valued identity product (D[m][n] = 100m+n+1) and
// decode each lane's (row,col) per accumulator register from the value itself.
// If decode fails (A/B operand mapping wrong -> unfixable by probe), fall back to
// the vector-FMA path -- now repaired: round 2 spent 256 v_cvt_f64_f32 per i0 per
// thread in the inner loop (cap ~66% FMA issue); converting once at staging and
// storing LDS as double makes the inner loop pure ds_read_b64 + v_fma_f64.
//
// ws layout: [0, 256KB)   : v-state, 32*1024 doubles (carried across T-chunks)
//            [256KB, ...) : current chunk buffer, Tc * 32 * 1024 doubles

#define NB 32
#define NI 1024
#define NO 1024
#define NT 1000
#define TT 128   // t-tile per block
#define OT 128   // o-tile per block
#define KI 16    // k (i) tile

typedef double d4 __attribute__((ext_vector_type(4)));

__global__ __launch_bounds__(256, 2)
void snn_gemm_f64v2(const float* __restrict__ x, const float* __restrict__ w,
                    double* __restrict__ cur, int t0, int len)
{
    __shared__ double As[KI][TT];   // 16 KB (i-major, t contiguous, doubles)
    __shared__ double Bs[KI][OT];   // 16 KB (i-major, o contiguous, doubles)
    __shared__ int s_ok;

    const int tid  = threadIdx.x;
    const int lane = tid & 63;
    const int wave = tid >> 6;           // 4 waves: 2x2 grid of 64x64 wave tiles
    const int wm   = (wave >> 1) * 64;   // t offset within block tile
    const int wn   = (wave & 1) * 64;    // o offset within block tile
    const int m16  = lane & 15;
    const int kq   = lane >> 4;          // 0..3

    const int tt0 = t0 + blockIdx.x * TT;
    const int o0  = blockIdx.y * OT;
    const int b   = blockIdx.z;
    const float* xb = x + (size_t)b * NI * NT;

    // ---- probe the D register->element mapping of v_mfma_f64_16x16x4f64 ----
    // A = identity (in 4 K-slices), B[k][n] = 100k+n+1  =>  D[m][n] = 100m+n+1.
    // All values are small exact integers in fp64, so each lane can decode which
    // (row,col) each of its 4 acc registers physically holds.
    d4 p = (d4)0.0;
#pragma unroll
    for (int s = 0; s < 4; ++s) {
        const double ap = (m16 == kq + 4 * s) ? 1.0 : 0.0;       // A[m=lane&15][k=lane>>4]
        const double bp = (double)(100 * (kq + 4 * s) + m16 + 1); // B[k=lane>>4][n=lane&15]
        p = __builtin_amdgcn_mfma_f64_16x16x4f64(ap, bp, p, 0, 0, 0);
    }
    int prow[4], pcol[4];
    bool ok = true;
#pragma unroll
    for (int r = 0; r < 4; ++r) {
        const double v = p[r];
        const int val = (int)v - 1;            // 100*m + n
        const int m = val / 100;
        const int n = val - m * 100;
        prow[r] = m; pcol[r] = n;
        ok = ok && (val >= 0) && (m < 16) && (n < 16) && ((double)(val + 1) == v);
    }
    if (tid == 0) s_ok = 1;
    __syncthreads();
    if (!ok) s_ok = 0;
    __syncthreads();
    const bool use_mfma = (s_ok != 0);   // block-uniform

    // staging decomposition: 16 rows x 128 cols per matrix, 2 float4 per thread per matrix
    const int sr = tid >> 5;         // rows sr and sr+8
    const int sc = (tid & 31) * 4;   // 0,4,...,124
    const int at = tt0 + sc;
    const int tend = t0 + len;

    if (use_mfma) {
        // ---------------- MFMA path ----------------
        d4 acc[4][4];
#pragma unroll
        for (int r = 0; r < 4; ++r)
#pragma unroll
            for (int c = 0; c < 4; ++c) acc[r][c] = (d4)0.0;

        for (int i0 = 0; i0 < NI; i0 += KI) {
            float4 a0 = make_float4(0.f, 0.f, 0.f, 0.f);
            float4 a1 = a0;
            if (at < NT) {
                a0 = *(const float4*)(xb + (size_t)(i0 + sr) * NT + at);
                a1 = *(const float4*)(xb + (size_t)(i0 + sr + 8) * NT + at);
            }
            const float4 b0 = *(const float4*)(w + (size_t)(i0 + sr) * NO + (o0 + sc));
            const float4 b1 = *(const float4*)(w + (size_t)(i0 + sr + 8) * NO + (o0 + sc));

            __syncthreads();
            As[sr][sc] = (double)a0.x; As[sr][sc + 1] = (double)a0.y;
            As[sr][sc + 2] = (double)a0.z; As[sr][sc + 3] = (double)a0.w;
            As[sr + 8][sc] = (double)a1.x; As[sr + 8][sc + 1] = (double)a1.y;
            As[sr + 8][sc + 2] = (double)a1.z; As[sr + 8][sc + 3] = (double)a1.w;
            Bs[sr][sc] = (double)b0.x; Bs[sr][sc + 1] = (double)b0.y;
            Bs[sr][sc + 2] = (double)b0.z; Bs[sr][sc + 3] = (double)b0.w;
            Bs[sr + 8][sc] = (double)b1.x; Bs[sr + 8][sc + 1] = (double)b1.y;
            Bs[sr + 8][sc + 2] = (double)b1.z; Bs[sr + 8][sc + 3] = (double)b1.w;
            __syncthreads();

#pragma unroll
            for (int k4 = 0; k4 < 4; ++k4) {
                const int kk = k4 * 4 + kq;
                double af[4], bf[4];
#pragma unroll
                for (int r = 0; r < 4; ++r) af[r] = As[kk][wm + r * 16 + m16];
#pragma unroll
                for (int c = 0; c < 4; ++c) bf[c] = Bs[kk][wn + c * 16 + m16];
#pragma unroll
                for (int r = 0; r < 4; ++r)
#pragma unroll
                    for (int c = 0; c < 4; ++c)
                        acc[r][c] = __builtin_amdgcn_mfma_f64_16x16x4f64(
                            af[r], bf[c], acc[r][c], 0, 0, 0);
            }
        }

        // store using the probed mapping: acc[rt][ct][j] = D_tile[prow[j]][pcol[j]]
#pragma unroll
        for (int rt = 0; rt < 4; ++rt) {
#pragma unroll
            for (int j = 0; j < 4; ++j) {
                const int tg = tt0 + wm + rt * 16 + prow[j];
                if (tg < tend) {
                    double* dst = cur + ((size_t)(tg - t0) * NB + b) * NO + o0 + wn;
#pragma unroll
                    for (int ct = 0; ct < 4; ++ct)
                        dst[ct * 16 + pcol[j]] = acc[rt][ct][j];
                }
            }
        }
    } else {
        // ---------------- vector-FMA fallback (repaired round 2) ----------------
        const int tx = tid & 15;   // o: tx*4+{0..3} and 64+tx*4+{0..3}
        const int ty = tid >> 4;   // t: ty*8+{0..7}
        double acc[8][8];
#pragma unroll
        for (int i = 0; i < 8; ++i)
#pragma unroll
            for (int j = 0; j < 8; ++j) acc[i][j] = 0.0;

        for (int i0 = 0; i0 < NI; i0 += KI) {
            float4 a0 = make_float4(0.f, 0.f, 0.f, 0.f);
            float4 a1 = a0;
            if (at < NT) {
                a0 = *(const float4*)(xb + (size_t)(i0 + sr) * NT + at);
                a1 = *(const float4*)(xb + (size_t)(i0 + sr + 8) * NT + at);
            }
            const float4 b0 = *(const float4*)(w + (size_t)(i0 + sr) * NO + (o0 + sc));
            const float4 b1 = *(const float4*)(w + (size_t)(i0 + sr + 8) * NO + (o0 + sc));

            __syncthreads();
            As[sr][sc] = (double)a0.x; As[sr][sc + 1] = (double)a0.y;
            As[sr][sc + 2] = (double)a0.z; As[sr][sc + 3] = (double)a0.w;
            As[sr + 8][sc] = (double)a1.x; As[sr + 8][sc + 1] = (double)a1.y;
            As[sr + 8][sc + 2] = (double)a1.z; As[sr + 8][sc + 3] = (double)a1.w;
            Bs[sr][sc] = (double)b0.x; Bs[sr][sc + 1] = (double)b0.y;
            Bs[sr][sc + 2] = (double)b0.z; Bs[sr][sc + 3] = (double)b0.w;
            Bs[sr + 8][sc] = (double)b1.x; Bs[sr + 8][sc + 1] = (double)b1.y;
            Bs[sr + 8][sc + 2] = (double)b1.z; Bs[sr + 8][sc + 3] = (double)b1.w;
            __syncthreads();

#pragma unroll
            for (int k = 0; k < KI; ++k) {
                double ad[8], bd[8];
#pragma unroll
                for (int u = 0; u < 8; ++u) ad[u] = As[k][ty * 8 + u];
#pragma unroll
                for (int u = 0; u < 4; ++u) {
                    bd[u]     = Bs[k][tx * 4 + u];
                    bd[u + 4] = Bs[k][tx * 4 + 64 + u];
                }
#pragma unroll
                for (int i = 0; i < 8; ++i)
#pragma unroll
                    for (int j = 0; j < 8; ++j)
                        acc[i][j] = fma(ad[i], bd[j], acc[i][j]);
            }
        }

#pragma unroll
        for (int i = 0; i < 8; ++i) {
            const int tg = tt0 + ty * 8 + i;
            if (tg < tend) {
                double* dst = cur + ((size_t)(tg - t0) * NB + b) * NO + o0;
                *(double2*)(dst + tx * 4)          = make_double2(acc[i][0], acc[i][1]);
                *(double2*)(dst + tx * 4 + 2)      = make_double2(acc[i][2], acc[i][3]);
                *(double2*)(dst + 64 + tx * 4)     = make_double2(acc[i][4], acc[i][5]);
                *(double2*)(dst + 64 + tx * 4 + 2) = make_double2(acc[i][6], acc[i][7]);
            }
        }
    }
}

// LIF scan: one thread per (b,o); cur chunk is [tc][b*NO+o] fp64; out is [b*NO+o][t] fp32.
__global__ __launch_bounds__(64)
void snn_scan_f64(const double* __restrict__ cur, float* __restrict__ out,
                  double* __restrict__ vstate, int t0, int len)
{
    const int gid = blockIdx.x * 64 + threadIdx.x;   // b*NO + o
    const double dt = 0.001 / 50.0;                  // MS / TAU, IEEE double, matches python

    double v = (t0 == 0) ? 0.0 : vstate[gid];
    const double* cp = cur + gid;                    // stride NB*NO per t-step
    float* op = out + (size_t)gid * NT + t0;         // thread-contiguous in t

    const size_t ts = (size_t)NB * NO;               // 32768
    const int ng = len >> 3;                         // len always multiple of 8

    double c[8], n[8];
#pragma unroll
    for (int j = 0; j < 8; ++j) c[j] = cp[(size_t)j * ts];
#pragma unroll
    for (int j = 0; j < 8; ++j) n[j] = (ng > 1) ? cp[(size_t)(8 + j) * ts] : 0.0;

    for (int g = 0; g < ng; ++g) {
        double m[8];
        if (g + 2 < ng) {
            const double* q = cp + (size_t)(8 * (g + 2)) * ts;
#pragma unroll
            for (int j = 0; j < 8; ++j) m[j] = q[(size_t)j * ts];
        } else {
#pragma unroll
            for (int j = 0; j < 8; ++j) m[j] = 0.0;
        }
        float s[8];
#pragma unroll
        for (int j = 0; j < 8; ++j) {
            v = v + (c[j] - v) * dt;
            const bool sp = (v >= 1.0);
            s[j] = sp ? 1.0f : 0.0f;
            if (sp) v = 0.0;
        }
        *(float4*)op       = make_float4(s[0], s[1], s[2], s[3]);
        *(float4*)(op + 4) = make_float4(s[4], s[5], s[6], s[7]);
        op += 8;
#pragma unroll
        for (int j = 0; j < 8; ++j) { c[j] = n[j]; n[j] = m[j]; }
    }
    vstate[gid] = v;
}

extern "C" void kernel_launch(void* const* d_in, const int* in_sizes, int n_in,
                              void* d_out, int out_size, void* d_ws, size_t ws_size,
                              hipStream_t stream)
{
    const float* x = (const float*)d_in[0];
    const float* w = (const float*)d_in[1];
    float* out = (float*)d_out;

    const size_t vbytes = (size_t)NB * NO * sizeof(double);   // 256 KB
    double* vstate = (double*)d_ws;
    double* curbuf = (double*)((char*)d_ws + vbytes);

    const size_t per_t = (size_t)NB * NO * sizeof(double);    // 256 KB per t-step
    size_t avail = (ws_size > vbytes) ? (ws_size - vbytes) : 0;
    int Tc = (int)((avail / per_t < (size_t)NT) ? (avail / per_t) : (size_t)NT);
    Tc &= ~7;                 // multiple of 8 (scan groups; 1000%8==0 so every len is too)
    if (Tc < 8) Tc = 8;

    for (int t0 = 0; t0 < NT; t0 += Tc) {
        const int len = (NT - t0 < Tc) ? (NT - t0) : Tc;
        dim3 gg((len + TT - 1) / TT, NO / OT, NB);
        snn_gemm_f64v2<<<gg, 256, 0, stream>>>(x, w, curbuf, t0, len);
        snn_scan_f64<<<(NB * NO) / 64, 64, 0, stream>>>(curbuf, out, vstate, t0, len);
    }
}

// Round 5
// 1303.882 us; speedup vs baseline: 1.3764x; 1.1694x over previous
//
#include <hip/hip_runtime.h>

// SNN layer: currents[t,b,o] = sum_i x[b,i,t] * w[i,o] in fp64 (binary spike output
// demands decision-exactness vs the numpy fp64 ref), then sequential LIF scan.
//
// Round 5: MFMA f64 path (probe-calibrated D layout, worked in round 4) with:
//  - LDS back to FLOAT (rounds 1-2 had 0 bank conflicts with float4 staging;
//    round 4's double-LDS had 3.4e7). v_cvt_f64_f32 moves to the fragment read,
//    where the VALU is 93% idle (MFMAs run on the matrix pipe).
//  - __launch_bounds__(256,3): 96 VGPR + 64 AGPR = 160 <= 170, so 3 blocks/CU
//    (was 2) -> a third block covers each block's barrier drain.
//
// ws layout: [0, 256KB)   : v-state, 32*1024 doubles (carried across T-chunks)
//            [256KB, ...) : current chunk buffer, Tc * 32 * 1024 doubles

#define NB 32
#define NI 1024
#define NO 1024
#define NT 1000
#define TT 128   // t-tile per block
#define OT 128   // o-tile per block
#define KI 16    // k (i) tile

typedef double d4 __attribute__((ext_vector_type(4)));

__global__ __launch_bounds__(256, 3)
void snn_gemm_mfma64(const float* __restrict__ x, const float* __restrict__ w,
                     double* __restrict__ cur, int t0, int len)
{
    __shared__ float As[KI][TT];   // 8 KB (i-major, t contiguous)
    __shared__ float Bs[KI][OT];   // 8 KB (i-major, o contiguous)

    const int tid  = threadIdx.x;
    const int lane = tid & 63;
    const int wave = tid >> 6;           // 4 waves: 2x2 grid of 64x64 wave tiles
    const int wm   = (wave >> 1) * 64;   // t offset within block tile
    const int wn   = (wave & 1) * 64;    // o offset within block tile
    const int m16  = lane & 15;
    const int kq   = lane >> 4;          // 0..3

    const int tt0 = t0 + blockIdx.x * TT;
    const int o0  = blockIdx.y * OT;
    const int b   = blockIdx.z;
    const float* xb = x + (size_t)b * NI * NT;

    // ---- probe the D register->element mapping of v_mfma_f64_16x16x4f64 ----
    // A = identity (4 K-slices), B[k][n] = 100k+n+1  =>  D[m][n] = 100m+n+1.
    // Exact small integers in fp64 -> each lane decodes (row,col) per acc register.
    // (Round 3 hard-coded the 32-bit-acc mapping and failed; this passed in r4.)
    d4 p = (d4)0.0;
#pragma unroll
    for (int s = 0; s < 4; ++s) {
        const double ap = (m16 == kq + 4 * s) ? 1.0 : 0.0;        // A[m=lane&15][k=lane>>4]
        const double bp = (double)(100 * (kq + 4 * s) + m16 + 1); // B[k=lane>>4][n=lane&15]
        p = __builtin_amdgcn_mfma_f64_16x16x4f64(ap, bp, p, 0, 0, 0);
    }
    int prow[4], pcol[4];
#pragma unroll
    for (int r = 0; r < 4; ++r) {
        const int val = ((int)p[r] - 1) & 0xffff;  // 100*m + n
        const int m = val / 100;
        prow[r] = m & 15;
        pcol[r] = (val - m * 100) & 15;
    }

    d4 acc[4][4];   // [t-tile][o-tile] -> AGPRs
#pragma unroll
    for (int r = 0; r < 4; ++r)
#pragma unroll
        for (int c = 0; c < 4; ++c) acc[r][c] = (d4)0.0;

    // staging: 16 rows x 128 cols per matrix, 2 float4 per thread per matrix
    const int sr = tid >> 5;         // rows sr and sr+8
    const int sc = (tid & 31) * 4;   // 0,4,...,124
    const int at = tt0 + sc;

    for (int i0 = 0; i0 < NI; i0 += KI) {
        float4 a0 = make_float4(0.f, 0.f, 0.f, 0.f);
        float4 a1 = a0;
        if (at < NT) {   // NT%4==0, at%4==0 -> whole float4 in bounds when at<NT
            a0 = *(const float4*)(xb + (size_t)(i0 + sr) * NT + at);
            a1 = *(const float4*)(xb + (size_t)(i0 + sr + 8) * NT + at);
        }
        const float4 b0 = *(const float4*)(w + (size_t)(i0 + sr) * NO + (o0 + sc));
        const float4 b1 = *(const float4*)(w + (size_t)(i0 + sr + 8) * NO + (o0 + sc));

        __syncthreads();   // previous iteration's LDS reads done
        *(float4*)&As[sr][sc]     = a0;    // 16B/lane consecutive -> conflict-free
        *(float4*)&As[sr + 8][sc] = a1;
        *(float4*)&Bs[sr][sc]     = b0;
        *(float4*)&Bs[sr + 8][sc] = b1;
        __syncthreads();

#pragma unroll
        for (int k4 = 0; k4 < 4; ++k4) {
            const int kk = k4 * 4 + kq;
            double af[4], bf[4];
#pragma unroll
            for (int r = 0; r < 4; ++r) af[r] = (double)As[kk][wm + r * 16 + m16];
#pragma unroll
            for (int c = 0; c < 4; ++c) bf[c] = (double)Bs[kk][wn + c * 16 + m16];
#pragma unroll
            for (int r = 0; r < 4; ++r)
#pragma unroll
                for (int c = 0; c < 4; ++c)
                    acc[r][c] = __builtin_amdgcn_mfma_f64_16x16x4f64(
                        af[r], bf[c], acc[r][c], 0, 0, 0);
        }
    }

    // store via probed mapping: acc[rt][ct][j] holds D_tile[prow[j]][pcol[j]]
    const int tend = t0 + len;
#pragma unroll
    for (int rt = 0; rt < 4; ++rt) {
#pragma unroll
        for (int j = 0; j < 4; ++j) {
            const int tg = tt0 + wm + rt * 16 + prow[j];
            if (tg < tend) {
                double* dst = cur + ((size_t)(tg - t0) * NB + b) * NO + o0 + wn;
#pragma unroll
                for (int ct = 0; ct < 4; ++ct)
                    dst[ct * 16 + pcol[j]] = acc[rt][ct][j];
            }
        }
    }
}

// LIF scan: one thread per (b,o); cur chunk is [tc][b*NO+o] fp64; out is [b*NO+o][t] fp32.
// Depth-16 prefetch (two 8-groups in flight) -> latency ceiling above HBM BW ceiling.
__global__ __launch_bounds__(64)
void snn_scan_f64(const double* __restrict__ cur, float* __restrict__ out,
                  double* __restrict__ vstate, int t0, int len)
{
    const int gid = blockIdx.x * 64 + threadIdx.x;   // b*NO + o
    const double dt = 0.001 / 50.0;                  // MS / TAU, IEEE double, matches python

    double v = (t0 == 0) ? 0.0 : vstate[gid];
    const double* cp = cur + gid;                    // stride NB*NO per t-step
    float* op = out + (size_t)gid * NT + t0;         // thread-contiguous in t

    const size_t ts = (size_t)NB * NO;               // 32768
    const int ng = len >> 3;                         // len always multiple of 8

    double c[8], n[8];
#pragma unroll
    for (int j = 0; j < 8; ++j) c[j] = cp[(size_t)j * ts];
#pragma unroll
    for (int j = 0; j < 8; ++j) n[j] = (ng > 1) ? cp[(size_t)(8 + j) * ts] : 0.0;

    for (int g = 0; g < ng; ++g) {
        double m[8];
        if (g + 2 < ng) {
            const double* q = cp + (size_t)(8 * (g + 2)) * ts;
#pragma unroll
            for (int j = 0; j < 8; ++j) m[j] = q[(size_t)j * ts];
        } else {
#pragma unroll
            for (int j = 0; j < 8; ++j) m[j] = 0.0;
        }
        float s[8];
#pragma unroll
        for (int j = 0; j < 8; ++j) {
            v = v + (c[j] - v) * dt;
            const bool sp = (v >= 1.0);
            s[j] = sp ? 1.0f : 0.0f;
            if (sp) v = 0.0;
        }
        *(float4*)op       = make_float4(s[0], s[1], s[2], s[3]);
        *(float4*)(op + 4) = make_float4(s[4], s[5], s[6], s[7]);
        op += 8;
#pragma unroll
        for (int j = 0; j < 8; ++j) { c[j] = n[j]; n[j] = m[j]; }
    }
    vstate[gid] = v;
}

extern "C" void kernel_launch(void* const* d_in, const int* in_sizes, int n_in,
                              void* d_out, int out_size, void* d_ws, size_t ws_size,
                              hipStream_t stream)
{
    const float* x = (const float*)d_in[0];
    const float* w = (const float*)d_in[1];
    float* out = (float*)d_out;

    const size_t vbytes = (size_t)NB * NO * sizeof(double);   // 256 KB
    double* vstate = (double*)d_ws;
    double* curbuf = (double*)((char*)d_ws + vbytes);

    const size_t per_t = (size_t)NB * NO * sizeof(double);    // 256 KB per t-step
    size_t avail = (ws_size > vbytes) ? (ws_size - vbytes) : 0;
    int Tc = (int)((avail / per_t < (size_t)NT) ? (avail / per_t) : (size_t)NT);
    Tc &= ~7;                 // multiple of 8 (scan groups; 1000%8==0 so every len is too)
    if (Tc < 8) Tc = 8;

    for (int t0 = 0; t0 < NT; t0 += Tc) {
        const int len = (NT - t0 < Tc) ? (NT - t0) : Tc;
        dim3 gg((len + TT - 1) / TT, NO / OT, NB);
        snn_gemm_mfma64<<<gg, 256, 0, stream>>>(x, w, curbuf, t0, len);
        snn_scan_f64<<<(NB * NO) / 64, 64, 0, stream>>>(curbuf, out, vstate, t0, len);
    }
}